// Round 1
// baseline (80.646 us; speedup 1.0000x reference)
//
#include <hip/hip_runtime.h>
#include <math.h>

// Problem dims (fixed by reference)
#define BDIM 2048
#define ODIM 256
#define IDIM 256

// Tiling
#define BT 32   // batch rows per block
#define OT 32   // output cols per block
#define JT 64   // j chunk staged in LDS

// out[b,o] = IDIM + C * sum_j 1/(D - 2at*cos(phi0 + x[b,j] + p[o,j]))
//   C = (t^2-1)(1-a^2),  D = 1+(at)^2
// cos(x'+p) = cos x' cos p - sin x' sin p  =>
//   den = D + (-2at*cos x')*cos p + (2at*sin x')*sin p
__global__ __launch_bounds__(256, 2)
void PhotonicCore_kernel(const float* __restrict__ X,   // [BDIM][IDIM]
                         const float* __restrict__ P,   // [ODIM][IDIM]
                         float* __restrict__ Out,       // [BDIM][ODIM]
                         float phi0, float m2at, float p2at,
                         float Dc, float Cnum) {
    // +1 float2 pad per row: row stride 130 dwords == 2 (mod 32) -> conflict-free
    __shared__ float2 As[BT][JT + 1];
    __shared__ float2 Ps[OT][JT + 1];

    const int tid = threadIdx.x;
    const int tx = tid & 15;        // o-group
    const int ty = tid >> 4;        // b-group (0..15)
    const int o0 = blockIdx.x * OT;
    const int b0 = blockIdx.y * BT;

    float acc00 = 0.f, acc01 = 0.f, acc10 = 0.f, acc11 = 0.f;

    for (int j0 = 0; j0 < IDIM; j0 += JT) {
        // ---- stage A margin: (-2at*cos(phi0+x), 2at*sin(phi0+x)) ----
        #pragma unroll
        for (int it = 0; it < (BT * JT) / 256; ++it) {
            int e  = tid + 256 * it;
            int r  = e >> 6;            // JT = 64
            int jj = e & (JT - 1);
            float x = X[(b0 + r) * IDIM + (j0 + jj)];
            float s, c;
            __sincosf(phi0 + x, &s, &c);
            As[r][jj] = make_float2(m2at * c, p2at * s);
        }
        // ---- stage P margin: (cos p, sin p) ----
        #pragma unroll
        for (int it = 0; it < (OT * JT) / 256; ++it) {
            int e  = tid + 256 * it;
            int r  = e >> 6;
            int jj = e & (JT - 1);
            float pv = P[(o0 + r) * IDIM + (j0 + jj)];
            float s, c;
            __sincosf(pv, &s, &c);
            Ps[r][jj] = make_float2(c, s);
        }
        __syncthreads();

        #pragma unroll 4
        for (int jj = 0; jj < JT; ++jj) {
            float2 a0 = As[ty][jj];
            float2 a1 = As[ty + 16][jj];
            float2 q0 = Ps[tx][jj];
            float2 q1 = Ps[tx + 16][jj];
            float d;
            d = fmaf(a0.x, q0.x, fmaf(a0.y, q0.y, Dc)); acc00 += __builtin_amdgcn_rcpf(d);
            d = fmaf(a0.x, q1.x, fmaf(a0.y, q1.y, Dc)); acc01 += __builtin_amdgcn_rcpf(d);
            d = fmaf(a1.x, q0.x, fmaf(a1.y, q0.y, Dc)); acc10 += __builtin_amdgcn_rcpf(d);
            d = fmaf(a1.x, q1.x, fmaf(a1.y, q1.y, Dc)); acc11 += __builtin_amdgcn_rcpf(d);
        }
        __syncthreads();
    }

    const float base = (float)IDIM;
    Out[(b0 + ty     ) * ODIM + (o0 + tx     )] = base + Cnum * acc00;
    Out[(b0 + ty     ) * ODIM + (o0 + tx + 16)] = base + Cnum * acc01;
    Out[(b0 + ty + 16) * ODIM + (o0 + tx     )] = base + Cnum * acc10;
    Out[(b0 + ty + 16) * ODIM + (o0 + tx + 16)] = base + Cnum * acc11;
}

extern "C" void kernel_launch(void* const* d_in, const int* in_sizes, int n_in,
                              void* d_out, int out_size, void* d_ws, size_t ws_size,
                              hipStream_t stream) {
    const float* X = (const float*)d_in[0];   // input_matrix [2048,256] f32
    const float* P = (const float*)d_in[1];   // phase_offset [256,256] f32
    float* Out = (float*)d_out;               // [2048,256] f32

    // Physics constants (double precision on host)
    const double RADIUS = 5e-6, KAPPA = 0.1, N_EFF = 3.48, LAMBDA = 1.55e-6, LOSS_A = 0.99;
    const double TWO_PI = 6.283185307179586476925286766559;
    const double t  = sqrt(1.0 - KAPPA);
    const double a  = LOSS_A;
    const double at = a * t;
    const double phi0 = fmod(TWO_PI * N_EFF * (TWO_PI * RADIUS) / LAMBDA, TWO_PI);
    const double D    = 1.0 + at * at;
    const double Cnum = (t * t - 1.0) * (1.0 - a * a);   // num - den (constant)

    dim3 grid(ODIM / OT, BDIM / BT);  // 8 x 64 = 512 blocks
    PhotonicCore_kernel<<<grid, 256, 0, stream>>>(
        X, P, Out,
        (float)phi0, (float)(-2.0 * at), (float)(2.0 * at),
        (float)D, (float)Cnum);
}